// Round 3
// baseline (307.965 us; speedup 1.0000x reference)
//
#include <hip/hip_runtime.h>
#include <stdint.h>

#define L_DIM 1024
#define N_DIM 32
#define C_DIM 512
#define M_DIM (L_DIM * N_DIM)   // 32768 rows for the GEMMs
#define EPS_BN 1e-5f

typedef __attribute__((ext_vector_type(8))) short bf16x8;
typedef __attribute__((ext_vector_type(4))) float f32x4;

__device__ __forceinline__ unsigned short f2bf(float f) {
  union { float f; unsigned int u; } a; a.f = f;
  unsigned int u = a.u;
  return (unsigned short)((u + 0x7FFFu + ((u >> 16) & 1u)) >> 16); // RNE
}
__device__ __forceinline__ float bf2f(unsigned short h) {
  union { float f; unsigned int u; } a; a.u = ((unsigned int)h) << 16;
  return a.f;
}

__device__ __forceinline__ void gl16(const void* g, void* l) {
  __builtin_amdgcn_global_load_lds(
      (const __attribute__((address_space(1))) unsigned int*)g,
      (__attribute__((address_space(3))) unsigned int*)l, 16, 0, 0);
}

// ---------------- split fp32 -> bf16 hi/lo ----------------
__global__ void k_split(const float* __restrict__ in, unsigned short* __restrict__ hi,
                        unsigned short* __restrict__ lo, int n4) {
  int i = blockIdx.x * blockDim.x + threadIdx.x;
  int stride = gridDim.x * blockDim.x;
  const float4* in4 = (const float4*)in;
  for (; i < n4; i += stride) {
    float4 v = in4[i];
    ushort4 h, l;
    h.x = f2bf(v.x); l.x = f2bf(v.x - bf2f(h.x));
    h.y = f2bf(v.y); l.y = f2bf(v.y - bf2f(h.y));
    h.z = f2bf(v.z); l.z = f2bf(v.z - bf2f(h.z));
    h.w = f2bf(v.w); l.w = f2bf(v.w - bf2f(h.w));
    ((ushort4*)hi)[i] = h;
    ((ushort4*)lo)[i] = l;
  }
}

// ---------------- bf16x3 MFMA GEMM: C = A * B^T + bias, fused BN stats ----------------
// A: (M x K) bf16 hi/lo pre-split. B: (N x K) bf16 hi/lo (= W layout). C: (M x N) fp32.
// Tile 128x128, BK=32, 256 threads = 4 waves (2x2), 4x4 frags 16x16x32, 3 MFMA passes.
// Double-buffered LDS (2x32KB), 2-phase pipeline: STAGE(next) -> compute(cur) -> barrier.
// XCD swizzle: all 4 bn-blocks of one bm land on the same XCD (blockIdx % 8 round-robin).
__global__ __launch_bounds__(256, 2)
void k_gemm(const unsigned short* __restrict__ Ahi, const unsigned short* __restrict__ Alo,
            const unsigned short* __restrict__ Bhi, const unsigned short* __restrict__ Blo,
            const float* __restrict__ bias, float* __restrict__ C,
            float* __restrict__ gsum, float* __restrict__ gsq,
            int M, int Nn, int K) {
  int d = blockIdx.x;
  int xcd = d & 7;
  int q = d >> 3;                    // 0..127
  int bm = xcd * 32 + (q >> 2);      // 256 A-panels, 32 consecutive per XCD
  int bn = q & 3;

  __shared__ unsigned short lds[2][16384];   // 2 x 32 KB: Ahi,Alo,Bhi,Blo tiles of 4096 ushort

  int tid  = threadIdx.x;
  int lane = tid & 63;
  int wave = tid >> 6;
  int wm = wave >> 1, wn = wave & 1;
  int lr = lane & 15;
  int lk = lane >> 4;

  f32x4 acc[4][4];
#pragma unroll
  for (int i = 0; i < 4; ++i)
#pragma unroll
    for (int j = 0; j < 4; ++j) acc[i][j] = (f32x4){0.f, 0.f, 0.f, 0.f};

  // staging slots: s = kc*128 + row (512 slots of 8 bf16); elem off = row*K + kc*8
  const int s0 = tid, s1 = tid + 256;
  const int a_off0 = (bm * 128 + (s0 & 127)) * K + ((s0 >> 7) << 3);
  const int a_off1 = (bm * 128 + (s1 & 127)) * K + ((s1 >> 7) << 3);
  const int b_off0 = (bn * 128 + (s0 & 127)) * K + ((s0 >> 7) << 3);
  const int b_off1 = (bn * 128 + (s1 & 127)) * K + ((s1 >> 7) << 3);

#define STAGE(buf, k0)                                            \
  do {                                                            \
    unsigned short* bAh = lds[buf];                               \
    unsigned short* bAl = lds[buf] + 4096;                        \
    unsigned short* bBh = lds[buf] + 8192;                        \
    unsigned short* bBl = lds[buf] + 12288;                       \
    gl16(Ahi + a_off0 + (k0), bAh + s0 * 8);                      \
    gl16(Ahi + a_off1 + (k0), bAh + s1 * 8);                      \
    gl16(Alo + a_off0 + (k0), bAl + s0 * 8);                      \
    gl16(Alo + a_off1 + (k0), bAl + s1 * 8);                      \
    gl16(Bhi + b_off0 + (k0), bBh + s0 * 8);                      \
    gl16(Bhi + b_off1 + (k0), bBh + s1 * 8);                      \
    gl16(Blo + b_off0 + (k0), bBl + s0 * 8);                      \
    gl16(Blo + b_off1 + (k0), bBl + s1 * 8);                      \
  } while (0)

  const int nt = K >> 5;             // 16 K-steps
  STAGE(0, 0);
  __syncthreads();                   // drain prologue loads

  for (int t = 0; t < nt; ++t) {
    int cur = t & 1;
    if (t + 1 < nt) STAGE(cur ^ 1, (t + 1) << 5);  // issue next tile first (latency hides under compute)

    const unsigned short* bAh = lds[cur];
    const unsigned short* bAl = lds[cur] + 4096;
    const unsigned short* bBh = lds[cur] + 8192;
    const unsigned short* bBl = lds[cur] + 12288;

    bf16x8 ah[4], al[4], bh[4], bl[4];
#pragma unroll
    for (int mi = 0; mi < 4; ++mi) {
      int slot = lk * 128 + wm * 64 + mi * 16 + lr;
      ah[mi] = *(const bf16x8*)(bAh + slot * 8);
      al[mi] = *(const bf16x8*)(bAl + slot * 8);
    }
#pragma unroll
    for (int nj = 0; nj < 4; ++nj) {
      int slot = lk * 128 + wn * 64 + nj * 16 + lr;
      bh[nj] = *(const bf16x8*)(bBh + slot * 8);
      bl[nj] = *(const bf16x8*)(bBl + slot * 8);
    }
#pragma unroll
    for (int mi = 0; mi < 4; ++mi)
#pragma unroll
      for (int nj = 0; nj < 4; ++nj)
        acc[mi][nj] = __builtin_amdgcn_mfma_f32_16x16x32_bf16(ah[mi], bh[nj], acc[mi][nj], 0, 0, 0);
#pragma unroll
    for (int mi = 0; mi < 4; ++mi)
#pragma unroll
      for (int nj = 0; nj < 4; ++nj)
        acc[mi][nj] = __builtin_amdgcn_mfma_f32_16x16x32_bf16(ah[mi], bl[nj], acc[mi][nj], 0, 0, 0);
#pragma unroll
    for (int mi = 0; mi < 4; ++mi)
#pragma unroll
      for (int nj = 0; nj < 4; ++nj)
        acc[mi][nj] = __builtin_amdgcn_mfma_f32_16x16x32_bf16(al[mi], bh[nj], acc[mi][nj], 0, 0, 0);

    __syncthreads();  // drains next-tile vmcnt + releases cur buffer for t+2 overwrite
  }

  // epilogue: C/D layout col = lane&15, row = (lane>>4)*4 + r; fused bias + BN partial stats
#pragma unroll
  for (int nj = 0; nj < 4; ++nj) {
    int gn = bn * 128 + wn * 64 + nj * 16 + lr;
    float bv = bias[gn];
    float s = 0.f, qq = 0.f;
#pragma unroll
    for (int mi = 0; mi < 4; ++mi) {
      int gm = bm * 128 + wm * 64 + mi * 16 + (lk << 2);
#pragma unroll
      for (int r = 0; r < 4; ++r) {
        float v = acc[mi][nj][r] + bv;
        C[(gm + r) * Nn + gn] = v;
        s += v; qq += v * v;
      }
    }
    s  += __shfl_xor(s, 16);  qq += __shfl_xor(qq, 16);
    s  += __shfl_xor(s, 32);  qq += __shfl_xor(qq, 32);
    if (lk == 0) {
      atomicAdd(&gsum[gn], s);
      atomicAdd(&gsq[gn], qq);
    }
  }
#undef STAGE
}

__global__ void k_finalize(const float* __restrict__ sum, const float* __restrict__ sq,
                           const float* __restrict__ g, const float* __restrict__ be,
                           float* __restrict__ scale, float* __restrict__ shift) {
  int c = threadIdx.x;                        // 512 threads
  float m = sum[c] * (1.0f / (float)M_DIM);
  float v = sq[c] * (1.0f / (float)M_DIM) - m * m;  // biased variance
  float sc = g[c] * rsqrtf(v + EPS_BN);
  scale[c] = sc;
  shift[c] = be[c] - m * sc;
}

// ---------------- BN + IndRNN, emit h as bf16 hi/lo for next GEMM ----------------
__global__ __launch_bounds__(64)
void k_indrnn_split(const float* __restrict__ y, const float* __restrict__ scale,
                    const float* __restrict__ shift, const float* __restrict__ u,
                    unsigned short* __restrict__ hhi, unsigned short* __restrict__ hlo) {
  int idx = blockIdx.x * 64 + threadIdx.x;    // (n,c): idx = n*512 + c, 16384 total
  int c = idx & 511;
  float sc = scale[c], sh = shift[c], uu = u[c];
  float h = 0.f;
  const float* py = y + idx;
  for (int l0 = 0; l0 < 1024; l0 += 32) {
    float v[32];
#pragma unroll
    for (int i = 0; i < 32; ++i) v[i] = py[(l0 + i) * 16384];
#pragma unroll
    for (int i = 0; i < 32; ++i) {
      float xt = v[i] * sc + sh;
      h = fmaxf(xt + uu * h, 0.f);
      int off = (l0 + i) * 16384 + idx;
      unsigned short hb = f2bf(h);
      hhi[off] = hb;
      hlo[off] = f2bf(h - bf2f(hb));
    }
  }
}

// ---------------- BN + IndRNN + residual, in place on d_out ----------------
__global__ __launch_bounds__(64)
void k_indrnn_res(float* __restrict__ y, const float* __restrict__ x,
                  const float* __restrict__ scale, const float* __restrict__ shift,
                  const float* __restrict__ u) {
  int idx = blockIdx.x * 64 + threadIdx.x;
  int c = idx & 511;
  float sc = scale[c], sh = shift[c], uu = u[c];
  float h = 0.f;
  for (int l0 = 0; l0 < 1024; l0 += 32) {
    float v[32], xs[32];
#pragma unroll
    for (int i = 0; i < 32; ++i) v[i] = y[(l0 + i) * 16384 + idx];
#pragma unroll
    for (int i = 0; i < 32; ++i) xs[i] = x[(l0 + i) * 16384 + idx];
#pragma unroll
    for (int i = 0; i < 32; ++i) {
      float xt = v[i] * sc + sh;
      h = fmaxf(xt + uu * h, 0.f);
      y[(l0 + i) * 16384 + idx] = h + xs[i];
    }
  }
}

extern "C" void kernel_launch(void* const* d_in, const int* in_sizes, int n_in,
                              void* d_out, int out_size, void* d_ws, size_t ws_size,
                              hipStream_t stream) {
  if (n_in < 11) return;
  const float* x   = (const float*)d_in[0];
  const float* W1  = (const float*)d_in[1];
  const float* b1  = (const float*)d_in[2];
  const float* g1  = (const float*)d_in[3];
  const float* be1 = (const float*)d_in[4];
  const float* u1  = (const float*)d_in[5];
  const float* W2  = (const float*)d_in[6];
  const float* b2  = (const float*)d_in[7];
  const float* g2  = (const float*)d_in[8];
  const float* be2 = (const float*)d_in[9];
  const float* u2  = (const float*)d_in[10];
  float* out = (float*)d_out;

  char* ws = (char*)d_ws;
  const size_t SZ_HALF = (size_t)M_DIM * C_DIM * sizeof(unsigned short); // 33,554,432 B
  const size_t SZ_W    = (size_t)C_DIM * C_DIM * sizeof(unsigned short); //    524,288 B
  unsigned short* Ahi  = (unsigned short*)(ws);             // x split; reused as h1 split
  unsigned short* Alo  = (unsigned short*)(ws + SZ_HALF);
  unsigned short* W1hi = (unsigned short*)(ws + 2 * SZ_HALF);
  unsigned short* W1lo = W1hi + C_DIM * C_DIM;
  unsigned short* W2hi = W1lo + C_DIM * C_DIM;
  unsigned short* W2lo = W2hi + C_DIM * C_DIM;
  float* stats = (float*)(ws + 2 * SZ_HALF + 4 * SZ_W);
  float* sum1 = stats,        *sq1 = stats + 512;
  float* sum2 = stats + 1024, *sq2 = stats + 1536;
  float* scale1 = stats + 2048, *shift1 = stats + 2560;
  float* scale2 = stats + 3072, *shift2 = stats + 3584;
  if (ws_size < 2 * SZ_HALF + 4 * SZ_W + 8 * 512 * sizeof(float)) return;

  hipMemsetAsync(stats, 0, 4 * 512 * sizeof(float), stream);  // sum1,sq1,sum2,sq2

  k_split<<<1024, 256, 0, stream>>>(x, Ahi, Alo, M_DIM * C_DIM / 4);
  k_split<<<256, 256, 0, stream>>>(W1, W1hi, W1lo, C_DIM * C_DIM / 4);
  k_split<<<256, 256, 0, stream>>>(W2, W2hi, W2lo, C_DIM * C_DIM / 4);

  dim3 gemmGrid((M_DIM / 128) * (C_DIM / 128));   // 1024 blocks = 8 XCD * 128
  k_gemm<<<gemmGrid, 256, 0, stream>>>(Ahi, Alo, W1hi, W1lo, b1, out, sum1, sq1, M_DIM, C_DIM, C_DIM);
  k_finalize<<<1, 512, 0, stream>>>(sum1, sq1, g1, be1, scale1, shift1);
  k_indrnn_split<<<256, 64, 0, stream>>>(out, scale1, shift1, u1, Ahi, Alo);

  k_gemm<<<gemmGrid, 256, 0, stream>>>(Ahi, Alo, W2hi, W2lo, b2, out, sum2, sq2, M_DIM, C_DIM, C_DIM);
  k_finalize<<<1, 512, 0, stream>>>(sum2, sq2, g2, be2, scale2, shift2);
  k_indrnn_res<<<256, 64, 0, stream>>>(out, x, scale2, shift2, u2);
}

// Round 4
// 276.580 us; speedup vs baseline: 1.1135x; 1.1135x over previous
//
#include <hip/hip_runtime.h>
#include <stdint.h>

#define L_DIM 1024
#define N_DIM 32
#define C_DIM 512
#define M_DIM (L_DIM * N_DIM)   // 32768 rows for the GEMMs
#define EPS_BN 1e-5f

typedef __attribute__((ext_vector_type(8))) short bf16x8;
typedef __attribute__((ext_vector_type(4))) float f32x4;

__device__ __forceinline__ unsigned short f2bf(float f) {
  union { float f; unsigned int u; } a; a.f = f;
  unsigned int u = a.u;
  return (unsigned short)((u + 0x7FFFu + ((u >> 16) & 1u)) >> 16); // RNE
}
__device__ __forceinline__ float bf2f(unsigned short h) {
  union { float f; unsigned int u; } a; a.u = ((unsigned int)h) << 16;
  return a.f;
}

__device__ __forceinline__ void gl16(const void* g, void* l) {
  __builtin_amdgcn_global_load_lds(
      (const __attribute__((address_space(1))) unsigned int*)g,
      (__attribute__((address_space(3))) unsigned int*)l, 16, 0, 0);
}

// ---------------- split fp32 -> bf16 hi/lo: x, W1, W2 in one kernel ----------------
__global__ void k_split_all(const float* __restrict__ x, const float* __restrict__ W1,
                            const float* __restrict__ W2,
                            unsigned short* __restrict__ Ahi, unsigned short* __restrict__ Alo,
                            unsigned short* __restrict__ W1hi, unsigned short* __restrict__ W1lo,
                            unsigned short* __restrict__ W2hi, unsigned short* __restrict__ W2lo) {
  const int NX = M_DIM * C_DIM / 4;      // 4,194,304 float4
  const int NW = C_DIM * C_DIM / 4;      // 65,536 float4
  int i = blockIdx.x * 256 + threadIdx.x;
  int stride = gridDim.x * 256;
  for (; i < NX + 2 * NW; i += stride) {
    const float4* src; unsigned short* dh; unsigned short* dl; int j;
    if (i < NX)            { src = (const float4*)x;  dh = Ahi;  dl = Alo;  j = i; }
    else if (i < NX + NW)  { src = (const float4*)W1; dh = W1hi; dl = W1lo; j = i - NX; }
    else                   { src = (const float4*)W2; dh = W2hi; dl = W2lo; j = i - NX - NW; }
    float4 v = src[j];
    ushort4 h, l;
    h.x = f2bf(v.x); l.x = f2bf(v.x - bf2f(h.x));
    h.y = f2bf(v.y); l.y = f2bf(v.y - bf2f(h.y));
    h.z = f2bf(v.z); l.z = f2bf(v.z - bf2f(h.z));
    h.w = f2bf(v.w); l.w = f2bf(v.w - bf2f(h.w));
    ((ushort4*)dh)[j] = h;
    ((ushort4*)dl)[j] = l;
  }
}

// ---------------- bf16x3 MFMA GEMM: C = A * B^T + bias, fused BN stats ----------------
// 256x256 tile, BK=32, 512 threads = 8 waves (2M x 4N), wave-tile 128x64, 16x16x32 MFMA x3 passes.
// Double-buffered 128KB LDS; 2-deep counted-vmcnt pipeline (vmcnt(8), never 0 in loop).
// Grid = 256 blocks = 1 block/CU. XCD swizzle: bn pair of each bm on same XCD.
__global__ __launch_bounds__(512, 2)
void k_gemm(const unsigned short* __restrict__ Ahi, const unsigned short* __restrict__ Alo,
            const unsigned short* __restrict__ Bhi, const unsigned short* __restrict__ Blo,
            const float* __restrict__ bias, float* __restrict__ C,
            float* __restrict__ gsum, float* __restrict__ gsq) {
  const int K = C_DIM;
  int d = blockIdx.x;
  int xcd = d & 7;
  int q = d >> 3;                  // 0..31
  int bm = xcd * 16 + (q >> 1);    // 0..127
  int bn = q & 1;                  // 0..1

  // per buffer 64KB = 4096 slots of 16B: [0,1024)=Ahi [1024,2048)=Alo [2048,3072)=Bhi [3072,4096)=Blo
  // slot within matrix: m = kc*256 + row  (kc = k-chunk of 8 elems)
  __shared__ unsigned short lds[2][32768];   // 128 KB total

  int tid  = threadIdx.x;
  int lane = tid & 63;
  int wave = tid >> 6;
  int wm = wave >> 2;              // 0..1
  int wn = wave & 3;               // 0..3
  int lr = lane & 15;
  int lk = lane >> 4;

  f32x4 acc[8][4];
#pragma unroll
  for (int i = 0; i < 8; ++i)
#pragma unroll
    for (int j = 0; j < 4; ++j) acc[i][j] = (f32x4){0.f, 0.f, 0.f, 0.f};

  // staging: thread covers slots tid+512*i (i=0..7); A offsets reused for hi and lo
  const int ra0 = tid & 255, ka0 = (tid >> 8) & 3;              // m = tid
  const int ra1 = (tid + 512) & 255, ka1 = ((tid + 512) >> 8) & 3;  // m = tid+512
  const int oa0 = (bm * 256 + ra0) * K + ka0 * 8;
  const int oa1 = (bm * 256 + ra1) * K + ka1 * 8;
  const int ob0 = (bn * 256 + ra0) * K + ka0 * 8;
  const int ob1 = (bn * 256 + ra1) * K + ka1 * 8;

#define STAGE(buf, kk)                                          \
  do {                                                          \
    unsigned short* Lb = lds[buf];                              \
    gl16(Ahi + oa0 + (kk), Lb + (tid) * 8);                     \
    gl16(Ahi + oa1 + (kk), Lb + (tid + 512) * 8);               \
    gl16(Alo + oa0 + (kk), Lb + (tid + 1024) * 8);              \
    gl16(Alo + oa1 + (kk), Lb + (tid + 1536) * 8);              \
    gl16(Bhi + ob0 + (kk), Lb + (tid + 2048) * 8);              \
    gl16(Bhi + ob1 + (kk), Lb + (tid + 2560) * 8);              \
    gl16(Blo + ob0 + (kk), Lb + (tid + 3072) * 8);              \
    gl16(Blo + ob1 + (kk), Lb + (tid + 3584) * 8);              \
  } while (0)

#define COMPUTE(buf)                                                          \
  do {                                                                        \
    const unsigned short* Lb = lds[buf];                                      \
    bf16x8 bh[4], bl[4], af[8];                                               \
    _Pragma("unroll")                                                         \
    for (int nj = 0; nj < 4; ++nj) {                                          \
      int slot = lk * 256 + wn * 64 + nj * 16 + lr;                           \
      bh[nj] = *(const bf16x8*)(Lb + 16384 + slot * 8);                       \
      bl[nj] = *(const bf16x8*)(Lb + 24576 + slot * 8);                       \
    }                                                                         \
    _Pragma("unroll")                                                         \
    for (int mi = 0; mi < 8; ++mi) {                                          \
      int slot = lk * 256 + wm * 128 + mi * 16 + lr;                          \
      af[mi] = *(const bf16x8*)(Lb + slot * 8);                               \
    }                                                                         \
    _Pragma("unroll")                                                         \
    for (int mi = 0; mi < 8; ++mi)                                            \
      _Pragma("unroll")                                                       \
      for (int nj = 0; nj < 4; ++nj)                                          \
        acc[mi][nj] = __builtin_amdgcn_mfma_f32_16x16x32_bf16(af[mi], bh[nj], acc[mi][nj], 0, 0, 0); \
    _Pragma("unroll")                                                         \
    for (int mi = 0; mi < 8; ++mi)                                            \
      _Pragma("unroll")                                                       \
      for (int nj = 0; nj < 4; ++nj)                                          \
        acc[mi][nj] = __builtin_amdgcn_mfma_f32_16x16x32_bf16(af[mi], bl[nj], acc[mi][nj], 0, 0, 0); \
    _Pragma("unroll")                                                         \
    for (int mi = 0; mi < 8; ++mi) {                                          \
      int slot = lk * 256 + wm * 128 + mi * 16 + lr;                          \
      af[mi] = *(const bf16x8*)(Lb + 8192 + slot * 8);                        \
    }                                                                         \
    _Pragma("unroll")                                                         \
    for (int mi = 0; mi < 8; ++mi)                                            \
      _Pragma("unroll")                                                       \
      for (int nj = 0; nj < 4; ++nj)                                          \
        acc[mi][nj] = __builtin_amdgcn_mfma_f32_16x16x32_bf16(af[mi], bh[nj], acc[mi][nj], 0, 0, 0); \
  } while (0)

  const int nt = K >> 5;                       // 16 K-steps
  STAGE(0, 0);
  STAGE(1, 32);                                // 16 loads/thread outstanding

  for (int t = 0; t < nt - 1; ++t) {
    asm volatile("s_waitcnt vmcnt(8)" ::: "memory");  // tile t landed; t+1's 8 in flight
    __builtin_amdgcn_sched_barrier(0);
    __builtin_amdgcn_s_barrier();              // every thread's tile-t loads landed
    COMPUTE(t & 1);
    __builtin_amdgcn_s_barrier();              // all waves done reading buf before overwrite
    if (t < nt - 2) STAGE(t & 1, (t + 2) << 5);
  }
  asm volatile("s_waitcnt vmcnt(0)" ::: "memory");    // final tile
  __builtin_amdgcn_sched_barrier(0);
  __builtin_amdgcn_s_barrier();
  COMPUTE((nt - 1) & 1);

  // epilogue: C/D layout col = lane&15, row = (lane>>4)*4 + r; fused bias + BN partial stats
#pragma unroll
  for (int nj = 0; nj < 4; ++nj) {
    int gn = bn * 256 + wn * 64 + nj * 16 + lr;
    float bv = bias[gn];
    float s = 0.f, qq = 0.f;
#pragma unroll
    for (int mi = 0; mi < 8; ++mi) {
      int gm = bm * 256 + wm * 128 + mi * 16 + (lk << 2);
#pragma unroll
      for (int r = 0; r < 4; ++r) {
        float v = acc[mi][nj][r] + bv;
        C[(gm + r) * C_DIM + gn] = v;
        s += v; qq += v * v;
      }
    }
    s  += __shfl_xor(s, 16);  qq += __shfl_xor(qq, 16);
    s  += __shfl_xor(s, 32);  qq += __shfl_xor(qq, 32);
    if (lk == 0) {
      atomicAdd(&gsum[gn], s);
      atomicAdd(&gsq[gn], qq);
    }
  }
#undef STAGE
#undef COMPUTE
}

// ---------------- BN(finalize inline) + IndRNN, emit h as bf16 hi/lo ----------------
__global__ __launch_bounds__(64, 1)
void k_indrnn_split(const float* __restrict__ y,
                    const float* __restrict__ gsum, const float* __restrict__ gsq,
                    const float* __restrict__ g, const float* __restrict__ be,
                    const float* __restrict__ u,
                    unsigned short* __restrict__ hhi, unsigned short* __restrict__ hlo) {
  int idx = blockIdx.x * 64 + threadIdx.x;    // (n,c): idx = n*512 + c
  int c = idx & 511;
  float m  = gsum[c] * (1.0f / (float)M_DIM);
  float vv = gsq[c]  * (1.0f / (float)M_DIM) - m * m;
  float sc = g[c] * rsqrtf(vv + EPS_BN);
  float sh = be[c] - m * sc;
  float uu = u[c];
  float h = 0.f;
  const float* py = y + idx;
  unsigned short* ph = hhi + idx;
  unsigned short* pl = hlo + idx;

  float bufA[64], bufB[64];
#define LOADC(B_, L0) _Pragma("unroll") for (int i = 0; i < 64; ++i) B_[i] = py[((L0) + i) * 16384];
#define PROC(B_, L0)                                              \
  _Pragma("unroll") for (int i = 0; i < 64; ++i) {                \
    float xt = B_[i] * sc + sh;                                   \
    h = fmaxf(fmaf(uu, h, xt), 0.f);                              \
    unsigned short hb = f2bf(h);                                  \
    ph[((L0) + i) * 16384] = hb;                                  \
    pl[((L0) + i) * 16384] = f2bf(h - bf2f(hb));                  \
  }
  LOADC(bufA, 0)
#pragma unroll
  for (int p = 0; p < 8; ++p) {
    int l0 = p * 128;
    LOADC(bufB, l0 + 64)
    PROC(bufA, l0)
    if (p < 7) { LOADC(bufA, l0 + 128) }
    PROC(bufB, l0 + 64)
  }
#undef LOADC
#undef PROC
}

// ---------------- BN(finalize inline) + IndRNN + residual, in place on d_out ----------------
__global__ __launch_bounds__(64, 1)
void k_indrnn_res(float* __restrict__ y, const float* __restrict__ x,
                  const float* __restrict__ gsum, const float* __restrict__ gsq,
                  const float* __restrict__ g, const float* __restrict__ be,
                  const float* __restrict__ u) {
  int idx = blockIdx.x * 64 + threadIdx.x;
  int c = idx & 511;
  float m  = gsum[c] * (1.0f / (float)M_DIM);
  float vv = gsq[c]  * (1.0f / (float)M_DIM) - m * m;
  float sc = g[c] * rsqrtf(vv + EPS_BN);
  float sh = be[c] - m * sc;
  float uu = u[c];
  float h = 0.f;
  float* py = y + idx;
  const float* px = x + idx;

  float yA[64], yB[64], xA[64], xB[64];
#define LOADC(BY, BX, L0)                                          \
  _Pragma("unroll") for (int i = 0; i < 64; ++i) {                 \
    BY[i] = py[((L0) + i) * 16384];                                \
    BX[i] = px[((L0) + i) * 16384];                                \
  }
#define PROC(BY, BX, L0)                                           \
  _Pragma("unroll") for (int i = 0; i < 64; ++i) {                 \
    float xt = BY[i] * sc + sh;                                    \
    h = fmaxf(fmaf(uu, h, xt), 0.f);                               \
    py[((L0) + i) * 16384] = h + BX[i];                            \
  }
  LOADC(yA, xA, 0)
#pragma unroll
  for (int p = 0; p < 8; ++p) {
    int l0 = p * 128;
    LOADC(yB, xB, l0 + 64)
    PROC(yA, xA, l0)
    if (p < 7) { LOADC(yA, xA, l0 + 128) }
    PROC(yB, xB, l0 + 64)
  }
#undef LOADC
#undef PROC
}

extern "C" void kernel_launch(void* const* d_in, const int* in_sizes, int n_in,
                              void* d_out, int out_size, void* d_ws, size_t ws_size,
                              hipStream_t stream) {
  if (n_in < 11) return;
  const float* x   = (const float*)d_in[0];
  const float* W1  = (const float*)d_in[1];
  const float* b1  = (const float*)d_in[2];
  const float* g1  = (const float*)d_in[3];
  const float* be1 = (const float*)d_in[4];
  const float* u1  = (const float*)d_in[5];
  const float* W2  = (const float*)d_in[6];
  const float* b2  = (const float*)d_in[7];
  const float* g2  = (const float*)d_in[8];
  const float* be2 = (const float*)d_in[9];
  const float* u2  = (const float*)d_in[10];
  float* out = (float*)d_out;

  char* ws = (char*)d_ws;
  const size_t SZ_HALF = (size_t)M_DIM * C_DIM * sizeof(unsigned short); // 33,554,432 B
  const size_t SZ_W    = (size_t)C_DIM * C_DIM * sizeof(unsigned short); //    524,288 B
  unsigned short* Ahi  = (unsigned short*)(ws);             // x split; reused as h1 split
  unsigned short* Alo  = (unsigned short*)(ws + SZ_HALF);
  unsigned short* W1hi = (unsigned short*)(ws + 2 * SZ_HALF);
  unsigned short* W1lo = W1hi + C_DIM * C_DIM;
  unsigned short* W2hi = W1lo + C_DIM * C_DIM;
  unsigned short* W2lo = W2hi + C_DIM * C_DIM;
  float* stats = (float*)(ws + 2 * SZ_HALF + 4 * SZ_W);
  float* sum1 = stats,        *sq1 = stats + 512;
  float* sum2 = stats + 1024, *sq2 = stats + 1536;
  if (ws_size < 2 * SZ_HALF + 4 * SZ_W + 4 * 512 * sizeof(float)) return;

  hipMemsetAsync(stats, 0, 4 * 512 * sizeof(float), stream);  // sum1,sq1,sum2,sq2

  k_split_all<<<2048, 256, 0, stream>>>(x, W1, W2, Ahi, Alo, W1hi, W1lo, W2hi, W2lo);

  dim3 gemmGrid(256);   // (32768/256) * (512/256) = 128*2; 1 block/CU
  k_gemm<<<gemmGrid, 512, 0, stream>>>(Ahi, Alo, W1hi, W1lo, b1, out, sum1, sq1);
  k_indrnn_split<<<256, 64, 0, stream>>>(out, sum1, sq1, g1, be1, u1, Ahi, Alo);

  k_gemm<<<gemmGrid, 512, 0, stream>>>(Ahi, Alo, W2hi, W2lo, b2, out, sum2, sq2);
  k_indrnn_res<<<256, 64, 0, stream>>>(out, x, sum2, sq2, g2, be2, u2);
}

// Round 5
// 230.387 us; speedup vs baseline: 1.3367x; 1.2005x over previous
//
#include <hip/hip_runtime.h>
#include <stdint.h>

#define L_DIM 1024
#define N_DIM 32
#define C_DIM 512
#define M_DIM (L_DIM * N_DIM)   // 32768 rows for the GEMMs
#define EPS_BN 1e-5f

typedef __attribute__((ext_vector_type(8))) short bf16x8;
typedef __attribute__((ext_vector_type(4))) float f32x4;

__device__ __forceinline__ unsigned short f2bf(float f) {
  union { float f; unsigned int u; } a; a.f = f;
  unsigned int u = a.u;
  return (unsigned short)((u + 0x7FFFu + ((u >> 16) & 1u)) >> 16); // RNE
}
__device__ __forceinline__ float bf2f(unsigned short h) {
  union { float f; unsigned int u; } a; a.u = ((unsigned int)h) << 16;
  return a.f;
}

__device__ __forceinline__ void gl16(const void* g, void* l) {
  __builtin_amdgcn_global_load_lds(
      (const __attribute__((address_space(1))) unsigned int*)g,
      (__attribute__((address_space(3))) unsigned int*)l, 16, 0, 0);
}

// ---------------- split fp32 -> bf16 hi/lo: x, W1, W2 in one kernel ----------------
__global__ void k_split_all(const float* __restrict__ x, const float* __restrict__ W1,
                            const float* __restrict__ W2,
                            unsigned short* __restrict__ Ahi, unsigned short* __restrict__ Alo,
                            unsigned short* __restrict__ W1hi, unsigned short* __restrict__ W1lo,
                            unsigned short* __restrict__ W2hi, unsigned short* __restrict__ W2lo) {
  const int NX = M_DIM * C_DIM / 4;      // 4,194,304 float4
  const int NW = C_DIM * C_DIM / 4;      // 65,536 float4
  int i = blockIdx.x * 256 + threadIdx.x;
  int stride = gridDim.x * 256;
  for (; i < NX + 2 * NW; i += stride) {
    const float4* src; unsigned short* dh; unsigned short* dl; int j;
    if (i < NX)            { src = (const float4*)x;  dh = Ahi;  dl = Alo;  j = i; }
    else if (i < NX + NW)  { src = (const float4*)W1; dh = W1hi; dl = W1lo; j = i - NX; }
    else                   { src = (const float4*)W2; dh = W2hi; dl = W2lo; j = i - NX - NW; }
    float4 v = src[j];
    ushort4 h, l;
    h.x = f2bf(v.x); l.x = f2bf(v.x - bf2f(h.x));
    h.y = f2bf(v.y); l.y = f2bf(v.y - bf2f(h.y));
    h.z = f2bf(v.z); l.z = f2bf(v.z - bf2f(h.z));
    h.w = f2bf(v.w); l.w = f2bf(v.w - bf2f(h.w));
    ((ushort4*)dh)[j] = h;
    ((ushort4*)dl)[j] = l;
  }
}

// ---------------- bf16x3 MFMA GEMM: C = A * B^T + bias, fused BN stats ----------------
// 256x256 tile, BK=32, 512 threads = 8 waves (2M x 4N), wave-tile 128x64, 16x16x32 MFMA x3 passes.
// Double-buffered 128KB LDS; 2-deep counted-vmcnt pipeline (vmcnt(8), never 0 in loop).
// Grid = 256 blocks = 1 block/CU. XCD swizzle: bn pair of each bm on same XCD.
__global__ __launch_bounds__(512, 2)
void k_gemm(const unsigned short* __restrict__ Ahi, const unsigned short* __restrict__ Alo,
            const unsigned short* __restrict__ Bhi, const unsigned short* __restrict__ Blo,
            const float* __restrict__ bias, float* __restrict__ C,
            float* __restrict__ gsum, float* __restrict__ gsq) {
  const int K = C_DIM;
  int d = blockIdx.x;
  int xcd = d & 7;
  int q = d >> 3;                  // 0..31
  int bm = xcd * 16 + (q >> 1);    // 0..127
  int bn = q & 1;                  // 0..1

  __shared__ unsigned short lds[2][32768];   // 128 KB total

  int tid  = threadIdx.x;
  int lane = tid & 63;
  int wave = tid >> 6;
  int wm = wave >> 2;              // 0..1
  int wn = wave & 3;               // 0..3
  int lr = lane & 15;
  int lk = lane >> 4;

  f32x4 acc[8][4];
#pragma unroll
  for (int i = 0; i < 8; ++i)
#pragma unroll
    for (int j = 0; j < 4; ++j) acc[i][j] = (f32x4){0.f, 0.f, 0.f, 0.f};

  const int ra0 = tid & 255, ka0 = (tid >> 8) & 3;
  const int ra1 = (tid + 512) & 255, ka1 = ((tid + 512) >> 8) & 3;
  const int oa0 = (bm * 256 + ra0) * K + ka0 * 8;
  const int oa1 = (bm * 256 + ra1) * K + ka1 * 8;
  const int ob0 = (bn * 256 + ra0) * K + ka0 * 8;
  const int ob1 = (bn * 256 + ra1) * K + ka1 * 8;

#define STAGE(buf, kk)                                          \
  do {                                                          \
    unsigned short* Lb = lds[buf];                              \
    gl16(Ahi + oa0 + (kk), Lb + (tid) * 8);                     \
    gl16(Ahi + oa1 + (kk), Lb + (tid + 512) * 8);               \
    gl16(Alo + oa0 + (kk), Lb + (tid + 1024) * 8);              \
    gl16(Alo + oa1 + (kk), Lb + (tid + 1536) * 8);              \
    gl16(Bhi + ob0 + (kk), Lb + (tid + 2048) * 8);              \
    gl16(Bhi + ob1 + (kk), Lb + (tid + 2560) * 8);              \
    gl16(Blo + ob0 + (kk), Lb + (tid + 3072) * 8);              \
    gl16(Blo + ob1 + (kk), Lb + (tid + 3584) * 8);              \
  } while (0)

#define COMPUTE(buf)                                                          \
  do {                                                                        \
    const unsigned short* Lb = lds[buf];                                      \
    bf16x8 bh[4], bl[4], af[8];                                               \
    _Pragma("unroll")                                                         \
    for (int nj = 0; nj < 4; ++nj) {                                          \
      int slot = lk * 256 + wn * 64 + nj * 16 + lr;                           \
      bh[nj] = *(const bf16x8*)(Lb + 16384 + slot * 8);                       \
      bl[nj] = *(const bf16x8*)(Lb + 24576 + slot * 8);                       \
    }                                                                         \
    _Pragma("unroll")                                                         \
    for (int mi = 0; mi < 8; ++mi) {                                          \
      int slot = lk * 256 + wm * 128 + mi * 16 + lr;                          \
      af[mi] = *(const bf16x8*)(Lb + slot * 8);                               \
    }                                                                         \
    _Pragma("unroll")                                                         \
    for (int mi = 0; mi < 8; ++mi)                                            \
      _Pragma("unroll")                                                       \
      for (int nj = 0; nj < 4; ++nj)                                          \
        acc[mi][nj] = __builtin_amdgcn_mfma_f32_16x16x32_bf16(af[mi], bh[nj], acc[mi][nj], 0, 0, 0); \
    _Pragma("unroll")                                                         \
    for (int mi = 0; mi < 8; ++mi)                                            \
      _Pragma("unroll")                                                       \
      for (int nj = 0; nj < 4; ++nj)                                          \
        acc[mi][nj] = __builtin_amdgcn_mfma_f32_16x16x32_bf16(af[mi], bl[nj], acc[mi][nj], 0, 0, 0); \
    _Pragma("unroll")                                                         \
    for (int mi = 0; mi < 8; ++mi) {                                          \
      int slot = lk * 256 + wm * 128 + mi * 16 + lr;                          \
      af[mi] = *(const bf16x8*)(Lb + 8192 + slot * 8);                        \
    }                                                                         \
    _Pragma("unroll")                                                         \
    for (int mi = 0; mi < 8; ++mi)                                            \
      _Pragma("unroll")                                                       \
      for (int nj = 0; nj < 4; ++nj)                                          \
        acc[mi][nj] = __builtin_amdgcn_mfma_f32_16x16x32_bf16(af[mi], bh[nj], acc[mi][nj], 0, 0, 0); \
  } while (0)

  const int nt = K >> 5;                       // 16 K-steps
  STAGE(0, 0);
  STAGE(1, 32);

  for (int t = 0; t < nt - 1; ++t) {
    asm volatile("s_waitcnt vmcnt(8)" ::: "memory");
    __builtin_amdgcn_sched_barrier(0);
    __builtin_amdgcn_s_barrier();
    COMPUTE(t & 1);
    __builtin_amdgcn_s_barrier();
    if (t < nt - 2) STAGE(t & 1, (t + 2) << 5);
  }
  asm volatile("s_waitcnt vmcnt(0)" ::: "memory");
  __builtin_amdgcn_sched_barrier(0);
  __builtin_amdgcn_s_barrier();
  COMPUTE((nt - 1) & 1);

#pragma unroll
  for (int nj = 0; nj < 4; ++nj) {
    int gn = bn * 256 + wn * 64 + nj * 16 + lr;
    float bv = bias[gn];
    float s = 0.f, qq = 0.f;
#pragma unroll
    for (int mi = 0; mi < 8; ++mi) {
      int gm = bm * 256 + wm * 128 + mi * 16 + (lk << 2);
#pragma unroll
      for (int r = 0; r < 4; ++r) {
        float v = acc[mi][nj][r] + bv;
        C[(gm + r) * C_DIM + gn] = v;
        s += v; qq += v * v;
      }
    }
    s  += __shfl_xor(s, 16);  qq += __shfl_xor(qq, 16);
    s  += __shfl_xor(s, 32);  qq += __shfl_xor(qq, 32);
    if (lk == 0) {
      atomicAdd(&gsum[gn], s);
      atomicAdd(&gsq[gn], qq);
    }
  }
#undef STAGE
#undef COMPUTE
}

// ---------------- parallel-scan IndRNN ----------------
// h_t = max(x_t + u h_{t-1}, 0). Maps h -> max(A + B h, M) form a monoid (B >= 0):
//   (A2,B2,M2) o (A1,B1,M1) = (A2 + B2*A1, B2*B1, max(A2 + B2*M1, M2))
// Identity on h>=0: (0,1,0). Block = 1024 threads = 16 waves; wave w owns rows
// [64w, 64w+64) of 64 chains (lanes). Phase1: per-segment triple. Phase2: LDS
// prefix compose. Phase3: exact sequential replay seeded with h_start.

// BN(finalize inline) + IndRNN, emit h as bf16 hi/lo
__global__ __launch_bounds__(1024, 4)
void k_indrnn_split(const float* __restrict__ y,
                    const float* __restrict__ gsum, const float* __restrict__ gsq,
                    const float* __restrict__ g, const float* __restrict__ be,
                    const float* __restrict__ u,
                    unsigned short* __restrict__ hhi, unsigned short* __restrict__ hlo) {
  __shared__ float tA[1024], tB[1024], tM[1024];
  int lane = threadIdx.x & 63;
  int w = threadIdx.x >> 6;                 // segment 0..15
  int chain = blockIdx.x * 64 + lane;       // (n,c) flat index
  int c = chain & 511;
  float m  = gsum[c] * (1.0f / (float)M_DIM);
  float vv = gsq[c]  * (1.0f / (float)M_DIM) - m * m;
  float sc = g[c] * rsqrtf(vv + EPS_BN);
  float sh = be[c] - m * sc;
  float uu = u[c];
  const float* py = y + chain;
  const int base = w * 64;

  // phase 1: segment triple
  float A = 0.f, Bc = 1.f, Mx = 0.f;
  for (int c0 = 0; c0 < 64; c0 += 16) {
    float vb[16];
#pragma unroll
    for (int i = 0; i < 16; ++i) vb[i] = py[(base + c0 + i) * 16384];
#pragma unroll
    for (int i = 0; i < 16; ++i) {
      float xt = fmaf(vb[i], sc, sh);
      A  = fmaf(uu, A, xt);
      Mx = fmaxf(fmaf(uu, Mx, xt), 0.f);
      Bc *= uu;
    }
  }
  tA[w * 64 + lane] = A; tB[w * 64 + lane] = Bc; tM[w * 64 + lane] = Mx;
  __syncthreads();

  // phase 2: prefix compose segments 0..w-1 (earliest applied first)
  float pA = 0.f, pB = 1.f, pM = 0.f;
  for (int s = 0; s < w; ++s) {
    float a = tA[s * 64 + lane], b = tB[s * 64 + lane], mm = tM[s * 64 + lane];
    pA = fmaf(b, pA, a);          // wrong order? see note: we need T_s o P
    pB = b * pB;
    pM = fmaxf(fmaf(b, pM, a), mm);
  }
  float h = fmaxf(pA, pM);        // h_start for this segment (h0 = 0)

  // phase 3: exact replay, emit bf16 hi/lo
  unsigned short* ph = hhi + chain;
  unsigned short* pl = hlo + chain;
  for (int c0 = 0; c0 < 64; c0 += 16) {
    float vb[16];
#pragma unroll
    for (int i = 0; i < 16; ++i) vb[i] = py[(base + c0 + i) * 16384];
#pragma unroll
    for (int i = 0; i < 16; ++i) {
      float xt = fmaf(vb[i], sc, sh);
      h = fmaxf(fmaf(uu, h, xt), 0.f);
      unsigned short hb = f2bf(h);
      int off = (base + c0 + i) * 16384;
      ph[off] = hb;
      pl[off] = f2bf(h - bf2f(hb));
    }
  }
}

// BN(finalize inline) + IndRNN + residual, in place on d_out
__global__ __launch_bounds__(1024, 4)
void k_indrnn_res(float* __restrict__ y, const float* __restrict__ x,
                  const float* __restrict__ gsum, const float* __restrict__ gsq,
                  const float* __restrict__ g, const float* __restrict__ be,
                  const float* __restrict__ u) {
  __shared__ float tA[1024], tB[1024], tM[1024];
  int lane = threadIdx.x & 63;
  int w = threadIdx.x >> 6;
  int chain = blockIdx.x * 64 + lane;
  int c = chain & 511;
  float m  = gsum[c] * (1.0f / (float)M_DIM);
  float vv = gsq[c]  * (1.0f / (float)M_DIM) - m * m;
  float sc = g[c] * rsqrtf(vv + EPS_BN);
  float sh = be[c] - m * sc;
  float uu = u[c];
  float* py = y + chain;
  const float* px = x + chain;
  const int base = w * 64;

  float A = 0.f, Bc = 1.f, Mx = 0.f;
  for (int c0 = 0; c0 < 64; c0 += 16) {
    float vb[16];
#pragma unroll
    for (int i = 0; i < 16; ++i) vb[i] = py[(base + c0 + i) * 16384];
#pragma unroll
    for (int i = 0; i < 16; ++i) {
      float xt = fmaf(vb[i], sc, sh);
      A  = fmaf(uu, A, xt);
      Mx = fmaxf(fmaf(uu, Mx, xt), 0.f);
      Bc *= uu;
    }
  }
  tA[w * 64 + lane] = A; tB[w * 64 + lane] = Bc; tM[w * 64 + lane] = Mx;
  __syncthreads();

  float pA = 0.f, pB = 1.f, pM = 0.f;
  for (int s = 0; s < w; ++s) {
    float a = tA[s * 64 + lane], b = tB[s * 64 + lane], mm = tM[s * 64 + lane];
    pA = fmaf(b, pA, a);
    pB = b * pB;
    pM = fmaxf(fmaf(b, pM, a), mm);
  }
  float h = fmaxf(pA, pM);

  for (int c0 = 0; c0 < 64; c0 += 16) {
    float vb[16], xb[16];
#pragma unroll
    for (int i = 0; i < 16; ++i) vb[i] = py[(base + c0 + i) * 16384];
#pragma unroll
    for (int i = 0; i < 16; ++i) xb[i] = px[(base + c0 + i) * 16384];
#pragma unroll
    for (int i = 0; i < 16; ++i) {
      float xt = fmaf(vb[i], sc, sh);
      h = fmaxf(fmaf(uu, h, xt), 0.f);
      py[(base + c0 + i) * 16384] = h + xb[i];
    }
  }
}

extern "C" void kernel_launch(void* const* d_in, const int* in_sizes, int n_in,
                              void* d_out, int out_size, void* d_ws, size_t ws_size,
                              hipStream_t stream) {
  if (n_in < 11) return;
  const float* x   = (const float*)d_in[0];
  const float* W1  = (const float*)d_in[1];
  const float* b1  = (const float*)d_in[2];
  const float* g1  = (const float*)d_in[3];
  const float* be1 = (const float*)d_in[4];
  const float* u1  = (const float*)d_in[5];
  const float* W2  = (const float*)d_in[6];
  const float* b2  = (const float*)d_in[7];
  const float* g2  = (const float*)d_in[8];
  const float* be2 = (const float*)d_in[9];
  const float* u2  = (const float*)d_in[10];
  float* out = (float*)d_out;

  char* ws = (char*)d_ws;
  const size_t SZ_HALF = (size_t)M_DIM * C_DIM * sizeof(unsigned short);
  const size_t SZ_W    = (size_t)C_DIM * C_DIM * sizeof(unsigned short);
  unsigned short* Ahi  = (unsigned short*)(ws);             // x split; reused as h1 split
  unsigned short* Alo  = (unsigned short*)(ws + SZ_HALF);
  unsigned short* W1hi = (unsigned short*)(ws + 2 * SZ_HALF);
  unsigned short* W1lo = W1hi + C_DIM * C_DIM;
  unsigned short* W2hi = W1lo + C_DIM * C_DIM;
  unsigned short* W2lo = W2hi + C_DIM * C_DIM;
  float* stats = (float*)(ws + 2 * SZ_HALF + 4 * SZ_W);
  float* sum1 = stats,        *sq1 = stats + 512;
  float* sum2 = stats + 1024, *sq2 = stats + 1536;
  if (ws_size < 2 * SZ_HALF + 4 * SZ_W + 4 * 512 * sizeof(float)) return;

  hipMemsetAsync(stats, 0, 4 * 512 * sizeof(float), stream);

  k_split_all<<<2048, 256, 0, stream>>>(x, W1, W2, Ahi, Alo, W1hi, W1lo, W2hi, W2lo);

  dim3 gemmGrid(256);
  k_gemm<<<gemmGrid, 512, 0, stream>>>(Ahi, Alo, W1hi, W1lo, b1, out, sum1, sq1);
  k_indrnn_split<<<256, 1024, 0, stream>>>(out, sum1, sq1, g1, be1, u1, Ahi, Alo);

  k_gemm<<<gemmGrid, 512, 0, stream>>>(Ahi, Alo, W2hi, W2lo, b2, out, sum2, sq2);
  k_indrnn_res<<<256, 1024, 0, stream>>>(out, x, sum2, sq2, g2, be2, u2);
}